// Round 2
// baseline (804.056 us; speedup 1.0000x reference)
//
#include <hip/hip_runtime.h>
#include <stdint.h>

#define NB 4
#define NS 16384
#define ND 192
#define NE 8
#define NT 1024
#define NKP 256
#define NI 384
#define LNEPS 1e-5f

typedef __attribute__((ext_vector_type(8))) short bf16x8;
typedef __attribute__((ext_vector_type(4))) float f32x4;

__device__ __forceinline__ unsigned short f2bf(float f){
  unsigned u = __float_as_uint(f);
  u += 0x7FFFu + ((u >> 16) & 1u);
  return (unsigned short)(u >> 16);
}

__device__ __forceinline__ f32x4 MFMA(bf16x8 a, bf16x8 b, f32x4 c){
  return __builtin_amdgcn_mfma_f32_16x16x32_bf16(a, b, c, 0, 0, 0);
}

// ---------- K1: per-patch mean/var + LN + gate logits + softmax (fused) ----------
__global__ __launch_bounds__(192) void k_stats(
    const float* __restrict__ x, const float* __restrict__ ln_g,
    const float* __restrict__ ln_b, const float* __restrict__ Wg,
    const float* __restrict__ Af, const float* __restrict__ cf,
    float* __restrict__ aff){
  int bt = blockIdx.x;
  int t = bt & (NT - 1);
  int d = threadIdx.x;
  int th = t >> 5, tw = t & 31;
  const float* xb = x + (size_t)(bt >> 10) * NS * ND + d;
  float v[16];
  float s = 0.f;
#pragma unroll
  for (int p = 0; p < 16; ++p){
    int srow = th * 512 + (p >> 2) * 128 + tw * 4 + (p & 3);
    v[p] = xb[(size_t)srow * ND];
    s += v[p];
  }
  float m = s * 0.0625f;
  float s2 = 0.f;
#pragma unroll
  for (int p = 0; p < 16; ++p){ float dv = v[p] - m; s2 += dv * dv; }
  float pv = s2 * 0.0625f;

  __shared__ float rbuf[192];
  __shared__ float mu_s, var_s;
  rbuf[d] = m; __syncthreads();
  for (int off = 96; off > 2; off >>= 1){
    if (d < off) rbuf[d] += rbuf[d + off];
    __syncthreads();
  }
  if (d == 0) mu_s = (rbuf[0] + rbuf[1] + rbuf[2]) * (1.f / 192.f);
  __syncthreads();
  float mu = mu_s;
  float dm = m - mu;
  rbuf[d] = dm * dm; __syncthreads();
  for (int off = 96; off > 2; off >>= 1){
    if (d < off) rbuf[d] += rbuf[d + off];
    __syncthreads();
  }
  if (d == 0) var_s = (rbuf[0] + rbuf[1] + rbuf[2]) * (1.f / 192.f);
  __syncthreads();
  float inv = 1.0f / sqrtf(var_s + LNEPS);
  float pl = dm * inv * ln_g[d] + ln_b[d];

  // gate logits: part[e] = pl*Wg[e,d] + pv*Af[e,d], reduce over d
  float part[NE];
#pragma unroll
  for (int e = 0; e < NE; ++e)
    part[e] = pl * Wg[e * 384 + d] + pv * Af[e * ND + d];
#pragma unroll
  for (int e = 0; e < NE; ++e)
#pragma unroll
    for (int off = 32; off > 0; off >>= 1)
      part[e] += __shfl_xor(part[e], off);
  __shared__ float red[3][NE];
  int wv = d >> 6, ln = d & 63;
  if (ln == 0){
#pragma unroll
    for (int e = 0; e < NE; ++e) red[wv][e] = part[e];
  }
  __syncthreads();
  if (d < NE){
    float lg = red[0][d] + red[1][d] + red[2][d] + cf[d];
    float mx = lg;
#pragma unroll
    for (int off = 1; off < 8; off <<= 1) mx = fmaxf(mx, __shfl_xor(mx, off));
    float ex = expf(lg - mx);
    float se = ex;
#pragma unroll
    for (int off = 1; off < 8; off <<= 1) se += __shfl_xor(se, off);
    aff[((size_t)(bt >> 10) * NE + d) * NT + t] = ex / se;
  }
}

// ---------- K2a: weights fp32 -> bf16 ----------
__global__ void k_wconv(const float* __restrict__ wg, const float* __restrict__ wu,
                        const float* __restrict__ wd, unsigned short* __restrict__ wgb,
                        unsigned short* __restrict__ wub, unsigned short* __restrict__ wdb){
  int i = blockIdx.x * 256 + threadIdx.x;
  if (i < NE * NI * ND){
    wgb[i] = f2bf(wg[i]);
    wub[i] = f2bf(wu[i]);
    wdb[i] = f2bf(wd[i]);
  }
}

// ---------- K2b: fold cplx matmul into gate: A[e][d] = sum_d' Wg[e,D+d']*Wc[d',d] ----------
__global__ void k_fuse(const float* __restrict__ Wc, const float* __restrict__ Wg,
                       const float* __restrict__ bc, const float* __restrict__ bg,
                       float* __restrict__ Af, float* __restrict__ cf){
  int idx = blockIdx.x * 128 + threadIdx.x;
  if (idx < NE * ND){
    int e = idx / ND, dd = idx % ND;
    float s = 0.f;
    for (int dp = 0; dp < ND; ++dp) s += Wg[e * 384 + ND + dp] * Wc[dp * ND + dd];
    Af[idx] = s;
  }
  if (idx < NE){
    float s = bg[idx];
    for (int dp = 0; dp < ND; ++dp) s += bc[dp] * Wg[idx * 384 + ND + dp];
    cf[idx] = s;
  }
}

// ---------- K4: exact-rank top-k (matches jax.lax.top_k tie semantics) ----------
__global__ __launch_bounds__(256) void k_topk(
    const float* __restrict__ aff, int* __restrict__ sidx,
    float* __restrict__ sval, float* __restrict__ twt){
  int be = blockIdx.x;
  int b = be >> 3;
  __shared__ float vals[NT];
  for (int t = threadIdx.x; t < NT; t += 256) vals[t] = aff[(size_t)be * NT + t];
  __syncthreads();
  int t0 = threadIdx.x, t1 = t0 + 256, t2 = t0 + 512, t3 = t0 + 768;
  float v0 = vals[t0], v1 = vals[t1], v2 = vals[t2], v3 = vals[t3];
  int r0 = 0, r1 = 0, r2 = 0, r3 = 0;
  for (int j = 0; j < NT; ++j){
    float vj = vals[j];
    r0 += (vj > v0) || (vj == v0 && j < t0);
    r1 += (vj > v1) || (vj == v1 && j < t1);
    r2 += (vj > v2) || (vj == v2 && j < t2);
    r3 += (vj > v3) || (vj == v3 && j < t3);
  }
  if (r0 < NKP){ sidx[be * NKP + r0] = t0; sval[be * NKP + r0] = v0; atomicAdd(&twt[b * NT + t0], v0); }
  if (r1 < NKP){ sidx[be * NKP + r1] = t1; sval[be * NKP + r1] = v1; atomicAdd(&twt[b * NT + t1], v1); }
  if (r2 < NKP){ sidx[be * NKP + r2] = t2; sval[be * NKP + r2] = v2; atomicAdd(&twt[b * NT + t2], v2); }
  if (r3 < NKP){ sidx[be * NKP + r3] = t3; sval[be * NKP + r3] = v3; atomicAdd(&twt[b * NT + t3], v3); }
}

// ---------- K5: wt_norm ----------
__global__ void k_wtn(const int* __restrict__ sidx, const float* __restrict__ sval,
                      const float* __restrict__ twt, float* __restrict__ wtn){
  int idx = blockIdx.x * 256 + threadIdx.x;
  int be = idx >> 8, b = be >> 3;
  int t = sidx[idx];
  wtn[idx] = sval[idx] / fmaxf(twt[b * NT + t], 1e-8f);
}

// ---------- K6: expert FFN (bf16 MFMA) + weighted scatter ----------
// 512 thr = 8 waves. One (b,e) x 16 patches per block, 4 internal iters of
// 64 rows. GU: 16 chunks (2 row-halves x 8 col-quarters of 48), 2 chunks/wave
// -> 48 VGPR live accum. Down: wave = 32 rows x 48 cols -> 24 VGPR.
// LDS: Xl 24KB + Hl 48KB = 72KB -> 2 blocks/CU; VGPR capped 128 -> 4 waves/SIMD.
__global__ __launch_bounds__(512, 4) void k_ffn(
    const float* __restrict__ x, const unsigned short* __restrict__ wgb,
    const unsigned short* __restrict__ wub, const unsigned short* __restrict__ wdb,
    const int* __restrict__ sidx, const float* __restrict__ wtn,
    float* __restrict__ out){
  int be = blockIdx.x, b = be >> 3, e = be & 7;
  int tid = threadIdx.x, w = tid >> 6, lane = tid & 63;
  int l15 = lane & 15, l4 = lane >> 4;
  __shared__ __align__(16) unsigned short Xl[64 * 192]; // swizzled bf16
  __shared__ __align__(16) unsigned short Hl[64 * 384]; // swizzled bf16

  for (int it = 0; it < 4; ++it){
    int jb = (blockIdx.y << 4) + (it << 2);

    { // gather X: 64 rows x 192 fp32 -> bf16 swizzled LDS (512 thr, 8/row)
      int row = tid >> 3, q = tid & 7;
      int j = jb + (row >> 4);
      int p = row & 15;
      int t = sidx[be * NKP + j];
      int th = t >> 5, tw = t & 31;
      int srow = th * 512 + (p >> 2) * 128 + tw * 4 + (p & 3);
      const float* src = x + ((size_t)(b * NS + srow)) * ND + q * 24;
      int rbase = row * 384, rsw = (row & 7) << 4;
#pragma unroll
      for (int c = 0; c < 6; ++c){
        float4 f = *reinterpret_cast<const float4*>(src + c * 4);
        uint2 pk;
        pk.x = (unsigned)f2bf(f.x) | ((unsigned)f2bf(f.y) << 16);
        pk.y = (unsigned)f2bf(f.z) | ((unsigned)f2bf(f.w) << 16);
        int byte = rbase + ((q * 48 + c * 8) ^ rsw);
        *reinterpret_cast<uint2*>(reinterpret_cast<char*>(Xl) + byte) = pk;
      }
    }
    __syncthreads();

    // ---- GU: 2 chunks per wave, chunk = 32 rows x 48 cols of G and U
    int rh = w & 1, cqb = w >> 1;
#pragma unroll
    for (int cc = 0; cc < 2; ++cc){
      int cq = cqb + cc * 4;
      f32x4 ag[2][3], au[2][3];
#pragma unroll
      for (int mt = 0; mt < 2; ++mt)
#pragma unroll
        for (int nt = 0; nt < 3; ++nt){
          ag[mt][nt] = f32x4{0.f, 0.f, 0.f, 0.f};
          au[mt][nt] = f32x4{0.f, 0.f, 0.f, 0.f};
        }
#pragma unroll
      for (int ks = 0; ks < 6; ++ks){
        bf16x8 a[2];
#pragma unroll
        for (int mt = 0; mt < 2; ++mt){
          int row = rh * 32 + mt * 16 + l15;
          int byte = row * 384 + ((ks * 64 + l4 * 16) ^ ((row & 7) << 4));
          a[mt] = *reinterpret_cast<const bf16x8*>(reinterpret_cast<const char*>(Xl) + byte);
        }
#pragma unroll
        for (int nt = 0; nt < 3; ++nt){
          int icol = cq * 48 + nt * 16 + l15;
          size_t off = ((size_t)(e * NI + icol)) * ND + ks * 32 + l4 * 8;
          bf16x8 bgf = *reinterpret_cast<const bf16x8*>(wgb + off);
          bf16x8 buf = *reinterpret_cast<const bf16x8*>(wub + off);
#pragma unroll
          for (int mt = 0; mt < 2; ++mt){
            ag[mt][nt] = MFMA(a[mt], bgf, ag[mt][nt]);
            au[mt][nt] = MFMA(a[mt], buf, au[mt][nt]);
          }
        }
      }
      // silu(G)*U -> bf16 -> swizzled Hl
#pragma unroll
      for (int mt = 0; mt < 2; ++mt)
#pragma unroll
        for (int nt = 0; nt < 3; ++nt)
#pragma unroll
          for (int r = 0; r < 4; ++r){
            float g = ag[mt][nt][r];
            float u = au[mt][nt][r];
            float h = g * u / (1.f + __expf(-g));
            int row = rh * 32 + mt * 16 + l4 * 4 + r;
            int col = cq * 48 + nt * 16 + l15;
            int byte = row * 768 + ((col * 2) ^ ((row & 7) << 4));
            *reinterpret_cast<unsigned short*>(reinterpret_cast<char*>(Hl) + byte) = f2bf(h);
          }
    }
    __syncthreads();

    // ---- down: wave = 32 rows x 48 cols
    int dq = w >> 1;
    f32x4 ao[2][3];
#pragma unroll
    for (int mt = 0; mt < 2; ++mt)
#pragma unroll
      for (int nt = 0; nt < 3; ++nt) ao[mt][nt] = f32x4{0.f, 0.f, 0.f, 0.f};
#pragma unroll
    for (int ks = 0; ks < 12; ++ks){
      bf16x8 a[2];
#pragma unroll
      for (int mt = 0; mt < 2; ++mt){
        int row = rh * 32 + mt * 16 + l15;
        int byte = row * 768 + ((ks * 64 + l4 * 16) ^ ((row & 7) << 4));
        a[mt] = *reinterpret_cast<const bf16x8*>(reinterpret_cast<const char*>(Hl) + byte);
      }
#pragma unroll
      for (int nt = 0; nt < 3; ++nt){
        int dcol = dq * 48 + nt * 16 + l15;
        size_t off = ((size_t)(e * ND + dcol)) * NI + ks * 32 + l4 * 8;
        bf16x8 bd = *reinterpret_cast<const bf16x8*>(wdb + off);
#pragma unroll
        for (int mt = 0; mt < 2; ++mt)
          ao[mt][nt] = MFMA(a[mt], bd, ao[mt][nt]);
      }
    }
    // ---- weighted scatter-add
#pragma unroll
    for (int mt = 0; mt < 2; ++mt){
      int j = jb + rh * 2 + mt;
      float wt = wtn[be * NKP + j];
      int t = sidx[be * NKP + j];
      int th = t >> 5, tw = t & 31;
#pragma unroll
      for (int r = 0; r < 4; ++r){
        int p = l4 * 4 + r;
        int srow = th * 512 + (p >> 2) * 128 + tw * 4 + (p & 3);
        float* op = out + ((size_t)(b * NS + srow)) * ND;
#pragma unroll
        for (int nt = 0; nt < 3; ++nt){
          int dcol = dq * 48 + nt * 16 + l15;
          atomicAdd(op + dcol, ao[mt][nt][r] * wt);
        }
      }
    }
    __syncthreads();
  }
}

extern "C" void kernel_launch(void* const* d_in, const int* in_sizes, int n_in,
                              void* d_out, int out_size, void* d_ws, size_t ws_size,
                              hipStream_t stream){
  const float* x     = (const float*)d_in[0];
  const float* ln_g  = (const float*)d_in[1];
  const float* ln_b  = (const float*)d_in[2];
  const float* Wc    = (const float*)d_in[3];
  const float* bc    = (const float*)d_in[4];
  const float* Wg    = (const float*)d_in[5];
  const float* bg    = (const float*)d_in[6];
  const float* Wgate = (const float*)d_in[7];
  const float* Wup   = (const float*)d_in[8];
  const float* Wdown = (const float*)d_in[9];
  float* out = (float*)d_out;
  (void)in_sizes; (void)n_in; (void)ws_size;

  char* ws = (char*)d_ws;
  size_t o = 0;
  auto carve = [&](size_t bytes) -> char* {
    char* p = ws + o; o += (bytes + 255) & ~(size_t)255; return p;
  };
  float* aff  = (float*)carve((size_t)NB * NE * NT * 4);
  float* Af   = (float*)carve(NE * ND * 4);
  float* cf   = (float*)carve(256);
  int*   sidx = (int*)carve(NB * NE * NKP * 4);
  float* sval = (float*)carve(NB * NE * NKP * 4);
  float* twt  = (float*)carve(NB * NT * 4);
  float* wtn  = (float*)carve(NB * NE * NKP * 4);
  unsigned short* wgb = (unsigned short*)carve((size_t)NE * NI * ND * 2);
  unsigned short* wub = (unsigned short*)carve((size_t)NE * NI * ND * 2);
  unsigned short* wdb = (unsigned short*)carve((size_t)NE * NI * ND * 2);

  hipMemsetAsync(out, 0, (size_t)out_size * sizeof(float), stream);
  hipMemsetAsync(twt, 0, NB * NT * 4, stream);

  k_wconv<<<(NE * NI * ND) / 256, 256, 0, stream>>>(Wgate, Wup, Wdown, wgb, wub, wdb);
  k_fuse<<<12, 128, 0, stream>>>(Wc, Wg, bc, bg, Af, cf);
  k_stats<<<NB * NT, 192, 0, stream>>>(x, ln_g, ln_b, Wg, Af, cf, aff);
  k_topk<<<NB * NE, 256, 0, stream>>>(aff, sidx, sval, twt);
  k_wtn<<<NB * NE * NKP / 256, 256, 0, stream>>>(sidx, sval, twt, wtn);
  dim3 gffn(NB * NE, NKP / 16, 1);
  k_ffn<<<gffn, 512, 0, stream>>>(x, wgb, wub, wdb, sidx, wtn, out);
}

// Round 3
// 318.693 us; speedup vs baseline: 2.5230x; 2.5230x over previous
//
#include <hip/hip_runtime.h>
#include <stdint.h>

#define NB 4
#define NS 16384
#define ND 192
#define NE 8
#define NT 1024
#define NKP 256
#define NI 384
#define LNEPS 1e-5f

typedef __attribute__((ext_vector_type(8))) short bf16x8;
typedef __attribute__((ext_vector_type(4))) float f32x4;

__device__ __forceinline__ unsigned short f2bf(float f){
  unsigned u = __float_as_uint(f);
  u += 0x7FFFu + ((u >> 16) & 1u);
  return (unsigned short)(u >> 16);
}
__device__ __forceinline__ float bf2f(unsigned short s){
  return __uint_as_float((unsigned)s << 16);
}

__device__ __forceinline__ f32x4 MFMA(bf16x8 a, bf16x8 b, f32x4 c){
  return __builtin_amdgcn_mfma_f32_16x16x32_bf16(a, b, c, 0, 0, 0);
}

// ---------- K1: per-patch mean/var + LN + gate logits + softmax (fused) ----------
__global__ __launch_bounds__(192) void k_stats(
    const float* __restrict__ x, const float* __restrict__ ln_g,
    const float* __restrict__ ln_b, const float* __restrict__ Wg,
    const float* __restrict__ Af, const float* __restrict__ cf,
    float* __restrict__ aff){
  int bt = blockIdx.x;
  int t = bt & (NT - 1);
  int d = threadIdx.x;
  int th = t >> 5, tw = t & 31;
  const float* xb = x + (size_t)(bt >> 10) * NS * ND + d;
  float v[16];
  float s = 0.f;
#pragma unroll
  for (int p = 0; p < 16; ++p){
    int srow = th * 512 + (p >> 2) * 128 + tw * 4 + (p & 3);
    v[p] = xb[(size_t)srow * ND];
    s += v[p];
  }
  float m = s * 0.0625f;
  float s2 = 0.f;
#pragma unroll
  for (int p = 0; p < 16; ++p){ float dv = v[p] - m; s2 += dv * dv; }
  float pv = s2 * 0.0625f;

  __shared__ float rbuf[192];
  __shared__ float mu_s, var_s;
  rbuf[d] = m; __syncthreads();
  for (int off = 96; off > 2; off >>= 1){
    if (d < off) rbuf[d] += rbuf[d + off];
    __syncthreads();
  }
  if (d == 0) mu_s = (rbuf[0] + rbuf[1] + rbuf[2]) * (1.f / 192.f);
  __syncthreads();
  float mu = mu_s;
  float dm = m - mu;
  rbuf[d] = dm * dm; __syncthreads();
  for (int off = 96; off > 2; off >>= 1){
    if (d < off) rbuf[d] += rbuf[d + off];
    __syncthreads();
  }
  if (d == 0) var_s = (rbuf[0] + rbuf[1] + rbuf[2]) * (1.f / 192.f);
  __syncthreads();
  float inv = 1.0f / sqrtf(var_s + LNEPS);
  float pl = dm * inv * ln_g[d] + ln_b[d];

  float part[NE];
#pragma unroll
  for (int e = 0; e < NE; ++e)
    part[e] = pl * Wg[e * 384 + d] + pv * Af[e * ND + d];
#pragma unroll
  for (int e = 0; e < NE; ++e)
#pragma unroll
    for (int off = 32; off > 0; off >>= 1)
      part[e] += __shfl_xor(part[e], off);
  __shared__ float red[3][NE];
  int wv = d >> 6, ln = d & 63;
  if (ln == 0){
#pragma unroll
    for (int e = 0; e < NE; ++e) red[wv][e] = part[e];
  }
  __syncthreads();
  if (d < NE){
    float lg = red[0][d] + red[1][d] + red[2][d] + cf[d];
    float mx = lg;
#pragma unroll
    for (int off = 1; off < 8; off <<= 1) mx = fmaxf(mx, __shfl_xor(mx, off));
    float ex = expf(lg - mx);
    float se = ex;
#pragma unroll
    for (int off = 1; off < 8; off <<= 1) se += __shfl_xor(se, off);
    aff[((size_t)(bt >> 10) * NE + d) * NT + t] = ex / se;
  }
}

// ---------- K2a: build interleaved GU weight (bf16) + down weight (bf16) ----------
// wgu[e][c][k], c = 32*g + 16*s + r  ->  (s?Wup:Wgate)[e][16*g + r][k]
__global__ void k_wconv(const float* __restrict__ wg, const float* __restrict__ wu,
                        const float* __restrict__ wd, unsigned short* __restrict__ wgu,
                        unsigned short* __restrict__ wdb){
  int i = blockIdx.x * 256 + threadIdx.x;
  if (i < NE * 768 * ND){
    int e = i / (768 * ND);
    int rem = i - e * 768 * ND;
    int c = rem / ND;
    int k = rem - c * ND;
    int g = c >> 5, s = (c >> 4) & 1, r = c & 15;
    const float* src = s ? wu : wg;
    wgu[i] = f2bf(src[((size_t)(e * NI + g * 16 + r)) * ND + k]);
  }
  if (i < NE * ND * NI){
    wdb[i] = f2bf(wd[i]);
  }
}

// ---------- K2b: fold cplx matmul into gate ----------
__global__ void k_fuse(const float* __restrict__ Wc, const float* __restrict__ Wg,
                       const float* __restrict__ bc, const float* __restrict__ bg,
                       float* __restrict__ Af, float* __restrict__ cf){
  int idx = blockIdx.x * 128 + threadIdx.x;
  if (idx < NE * ND){
    int e = idx / ND, dd = idx % ND;
    float s = 0.f;
    for (int dp = 0; dp < ND; ++dp) s += Wg[e * 384 + ND + dp] * Wc[dp * ND + dd];
    Af[idx] = s;
  }
  if (idx < NE){
    float s = bg[idx];
    for (int dp = 0; dp < ND; ++dp) s += bc[dp] * Wg[idx * 384 + ND + dp];
    cf[idx] = s;
  }
}

// ---------- K4: exact-rank top-k + inverse index ----------
__global__ __launch_bounds__(256) void k_topk(
    const float* __restrict__ aff, int* __restrict__ sidx,
    float* __restrict__ sval, float* __restrict__ twt,
    int* __restrict__ cnt, int* __restrict__ inv){
  int be = blockIdx.x;
  int b = be >> 3, e = be & 7;
  __shared__ float vals[NT];
  for (int t = threadIdx.x; t < NT; t += 256) vals[t] = aff[(size_t)be * NT + t];
  __syncthreads();
  int t0 = threadIdx.x, t1 = t0 + 256, t2 = t0 + 512, t3 = t0 + 768;
  float v0 = vals[t0], v1 = vals[t1], v2 = vals[t2], v3 = vals[t3];
  int r0 = 0, r1 = 0, r2 = 0, r3 = 0;
  for (int j = 0; j < NT; ++j){
    float vj = vals[j];
    r0 += (vj > v0) || (vj == v0 && j < t0);
    r1 += (vj > v1) || (vj == v1 && j < t1);
    r2 += (vj > v2) || (vj == v2 && j < t2);
    r3 += (vj > v3) || (vj == v3 && j < t3);
  }
  if (r0 < NKP){ sidx[be * NKP + r0] = t0; sval[be * NKP + r0] = v0; atomicAdd(&twt[b * NT + t0], v0);
                 int p = atomicAdd(&cnt[b * NT + t0], 1); inv[(b * NT + t0) * 8 + p] = (e << 16) | r0; }
  if (r1 < NKP){ sidx[be * NKP + r1] = t1; sval[be * NKP + r1] = v1; atomicAdd(&twt[b * NT + t1], v1);
                 int p = atomicAdd(&cnt[b * NT + t1], 1); inv[(b * NT + t1) * 8 + p] = (e << 16) | r1; }
  if (r2 < NKP){ sidx[be * NKP + r2] = t2; sval[be * NKP + r2] = v2; atomicAdd(&twt[b * NT + t2], v2);
                 int p = atomicAdd(&cnt[b * NT + t2], 1); inv[(b * NT + t2) * 8 + p] = (e << 16) | r2; }
  if (r3 < NKP){ sidx[be * NKP + r3] = t3; sval[be * NKP + r3] = v3; atomicAdd(&twt[b * NT + t3], v3);
                 int p = atomicAdd(&cnt[b * NT + t3], 1); inv[(b * NT + t3) * 8 + p] = (e << 16) | r3; }
}

// ---------- K5: wt_norm ----------
__global__ void k_wtn(const int* __restrict__ sidx, const float* __restrict__ sval,
                      const float* __restrict__ twt, float* __restrict__ wtn){
  int idx = blockIdx.x * 256 + threadIdx.x;
  int be = idx >> 8, b = be >> 3;
  int t = sidx[idx];
  wtn[idx] = sval[idx] / fmaxf(twt[b * NT + t], 1e-8f);
}

// ---------- K6: expert FFN (bf16 MFMA) -> weighted contrib (bf16, coalesced) ----------
// 256 thr = 4 waves. Block = one (b,e) x 64 rows (4 selections). grid (32 be, 64 tiles):
// blockIdx.x & 7 == e -> expert pinned per XCD for L2 weight residency.
// GU: interleaved wgu, 2 passes, wave tile 64x96 (acc 96 VGPR, 24 MFMA : 6 B-loads / ks).
// Down: wave tile 64x48. Two __syncthreads total.
__global__ __launch_bounds__(256) void k_ffn(
    const float* __restrict__ x, const unsigned short* __restrict__ wgu,
    const unsigned short* __restrict__ wdb,
    const int* __restrict__ sidx, const float* __restrict__ wtn,
    unsigned short* __restrict__ contrib){
  int be = blockIdx.x, b = be >> 3, e = be & 7;
  int tile = blockIdx.y;
  int jb = tile * 4;
  int tid = threadIdx.x, w = tid >> 6, lane = tid & 63;
  int l15 = lane & 15, l4 = lane >> 4;
  __shared__ __align__(16) unsigned short Xl[64 * 192]; // swizzled bf16
  __shared__ __align__(16) unsigned short Hl[64 * 384]; // swizzled bf16

  { // gather X: 64 rows x 192 fp32 -> bf16 swizzled (4 thr/row, 48 cols each)
    int row = tid >> 2, q = tid & 3;
    int j = jb + (row >> 4), p = row & 15;
    int t = sidx[be * NKP + j];
    int th = t >> 5, tw = t & 31;
    int srow = th * 512 + (p >> 2) * 128 + tw * 4 + (p & 3);
    const float* src = x + ((size_t)(b * NS + srow)) * ND + q * 48;
    int rbase = row * 384, rsw = (row & 7) << 4;
#pragma unroll
    for (int c = 0; c < 6; ++c){
      float4 f0 = *reinterpret_cast<const float4*>(src + c * 8);
      float4 f1 = *reinterpret_cast<const float4*>(src + c * 8 + 4);
      uint4 pk;
      pk.x = (unsigned)f2bf(f0.x) | ((unsigned)f2bf(f0.y) << 16);
      pk.y = (unsigned)f2bf(f0.z) | ((unsigned)f2bf(f0.w) << 16);
      pk.z = (unsigned)f2bf(f1.x) | ((unsigned)f2bf(f1.y) << 16);
      pk.w = (unsigned)f2bf(f1.z) | ((unsigned)f2bf(f1.w) << 16);
      int byte = rbase + (((q * 48 + c * 8) * 2) ^ rsw);
      *reinterpret_cast<uint4*>(reinterpret_cast<char*>(Xl) + byte) = pk;
    }
  }
  __syncthreads();

  // ---- GU: C = X @ Wgu^T over interleaved 768 cols, 2 passes of 384
#pragma unroll
  for (int np = 0; np < 2; ++np){
    f32x4 acc[4][6];
#pragma unroll
    for (int mt = 0; mt < 4; ++mt)
#pragma unroll
      for (int nt = 0; nt < 6; ++nt) acc[mt][nt] = f32x4{0.f, 0.f, 0.f, 0.f};
#pragma unroll
    for (int ks = 0; ks < 6; ++ks){
      bf16x8 a[4];
#pragma unroll
      for (int mt = 0; mt < 4; ++mt){
        int row = mt * 16 + l15;
        int byte = row * 384 + ((ks * 64 + l4 * 16) ^ ((row & 7) << 4));
        a[mt] = *reinterpret_cast<const bf16x8*>(reinterpret_cast<const char*>(Xl) + byte);
      }
#pragma unroll
      for (int nt = 0; nt < 6; ++nt){
        int c = np * 384 + w * 96 + nt * 16 + l15;
        bf16x8 bb = *reinterpret_cast<const bf16x8*>(
            wgu + ((size_t)(e * 768 + c)) * ND + ks * 32 + l4 * 8);
#pragma unroll
        for (int mt = 0; mt < 4; ++mt)
          acc[mt][nt] = MFMA(a[mt], bb, acc[mt][nt]);
      }
    }
    // silu(G)*U -> bf16 -> swizzled Hl (nt even = gate, nt odd = up)
#pragma unroll
    for (int gp = 0; gp < 3; ++gp)
#pragma unroll
      for (int mt = 0; mt < 4; ++mt)
#pragma unroll
        for (int r = 0; r < 4; ++r){
          float g = acc[mt][2 * gp][r];
          float u = acc[mt][2 * gp + 1][r];
          float h = g * u / (1.f + __expf(-g));
          int hrow = mt * 16 + l4 * 4 + r;
          int hcol = np * 192 + w * 48 + gp * 16 + l15;
          int byte = hrow * 768 + ((hcol * 2) ^ ((hrow & 7) << 4));
          *reinterpret_cast<unsigned short*>(reinterpret_cast<char*>(Hl) + byte) = f2bf(h);
        }
  }
  __syncthreads();

  // ---- down: O = H @ Wdown^T ; wave tile 64 x 48
  f32x4 ao[4][3];
#pragma unroll
  for (int mt = 0; mt < 4; ++mt)
#pragma unroll
    for (int nt = 0; nt < 3; ++nt) ao[mt][nt] = f32x4{0.f, 0.f, 0.f, 0.f};
#pragma unroll
  for (int ks = 0; ks < 12; ++ks){
    bf16x8 a[4];
#pragma unroll
    for (int mt = 0; mt < 4; ++mt){
      int row = mt * 16 + l15;
      int byte = row * 768 + ((ks * 64 + l4 * 16) ^ ((row & 7) << 4));
      a[mt] = *reinterpret_cast<const bf16x8*>(reinterpret_cast<const char*>(Hl) + byte);
    }
#pragma unroll
    for (int nt = 0; nt < 3; ++nt){
      int dcol = w * 48 + nt * 16 + l15;
      bf16x8 bd = *reinterpret_cast<const bf16x8*>(
          wdb + ((size_t)(e * ND + dcol)) * NI + ks * 32 + l4 * 8);
#pragma unroll
      for (int mt = 0; mt < 4; ++mt)
        ao[mt][nt] = MFMA(a[mt], bd, ao[mt][nt]);
    }
  }
  // ---- weighted contrib store (coalesced bf16)
#pragma unroll
  for (int mt = 0; mt < 4; ++mt){
    float wt = wtn[be * NKP + jb + mt];
#pragma unroll
    for (int r = 0; r < 4; ++r){
      int mrow = tile * 64 + mt * 16 + l4 * 4 + r;
      unsigned short* dst = contrib + ((size_t)be * 4096 + mrow) * ND;
#pragma unroll
      for (int nt = 0; nt < 3; ++nt){
        int dcol = w * 48 + nt * 16 + l15;
        dst[dcol] = f2bf(ao[mt][nt][r] * wt);
      }
    }
  }
}

// ---------- K7: per-token gather-sum of contributions -> out ----------
__global__ __launch_bounds__(256) void k_scatter(
    const unsigned short* __restrict__ contrib, const int* __restrict__ cnt,
    const int* __restrict__ inv, float* __restrict__ out){
  int bt = blockIdx.x;
  int b = bt >> 10, t = bt & (NT - 1);
  __shared__ int s_cnt;
  __shared__ int s_ent[8];
  if (threadIdx.x == 0) s_cnt = cnt[bt];
  if (threadIdx.x < 8) s_ent[threadIdx.x] = inv[bt * 8 + threadIdx.x];
  __syncthreads();
  int n = s_cnt;
  int p = threadIdx.x >> 4, dq = threadIdx.x & 15;
  int d0 = dq * 12;
  float acc[12];
#pragma unroll
  for (int i = 0; i < 12; ++i) acc[i] = 0.f;
  for (int i = 0; i < n; ++i){
    int ent = s_ent[i];
    int e = ent >> 16, r = ent & 0xffff;
    const unsigned short* src = contrib +
        ((((size_t)((b * 8 + e) * NKP + r)) * 16 + p) * ND + d0);
#pragma unroll
    for (int c = 0; c < 3; ++c){
      uint2 v = *reinterpret_cast<const uint2*>(src + c * 4);
      acc[c * 4 + 0] += bf2f((unsigned short)(v.x & 0xffff));
      acc[c * 4 + 1] += bf2f((unsigned short)(v.x >> 16));
      acc[c * 4 + 2] += bf2f((unsigned short)(v.y & 0xffff));
      acc[c * 4 + 3] += bf2f((unsigned short)(v.y >> 16));
    }
  }
  int th = t >> 5, tw = t & 31;
  int srow = th * 512 + (p >> 2) * 128 + tw * 4 + (p & 3);
  float* dst = out + ((size_t)(b * NS + srow)) * ND + d0;
#pragma unroll
  for (int c = 0; c < 3; ++c){
    float4 o;
    o.x = acc[c * 4 + 0]; o.y = acc[c * 4 + 1];
    o.z = acc[c * 4 + 2]; o.w = acc[c * 4 + 3];
    *reinterpret_cast<float4*>(dst + c * 4) = o;
  }
}

extern "C" void kernel_launch(void* const* d_in, const int* in_sizes, int n_in,
                              void* d_out, int out_size, void* d_ws, size_t ws_size,
                              hipStream_t stream){
  const float* x     = (const float*)d_in[0];
  const float* ln_g  = (const float*)d_in[1];
  const float* ln_b  = (const float*)d_in[2];
  const float* Wc    = (const float*)d_in[3];
  const float* bc    = (const float*)d_in[4];
  const float* Wg    = (const float*)d_in[5];
  const float* bg    = (const float*)d_in[6];
  const float* Wgate = (const float*)d_in[7];
  const float* Wup   = (const float*)d_in[8];
  const float* Wdown = (const float*)d_in[9];
  float* out = (float*)d_out;
  (void)in_sizes; (void)n_in; (void)ws_size; (void)out_size;

  char* ws = (char*)d_ws;
  size_t o = 0;
  auto carve = [&](size_t bytes) -> char* {
    char* p = ws + o; o += (bytes + 255) & ~(size_t)255; return p;
  };
  float* aff  = (float*)carve((size_t)NB * NE * NT * 4);
  float* Af   = (float*)carve(NE * ND * 4);
  float* cf   = (float*)carve(256);
  int*   sidx = (int*)carve(NB * NE * NKP * 4);
  float* sval = (float*)carve(NB * NE * NKP * 4);
  float* twt  = (float*)carve(NB * NT * 4);
  float* wtn  = (float*)carve(NB * NE * NKP * 4);
  int*   cnt  = (int*)carve(NB * NT * 4);
  int*   inv  = (int*)carve(NB * NT * 8 * 4);
  unsigned short* wgu = (unsigned short*)carve((size_t)NE * 768 * ND * 2);
  unsigned short* wdb = (unsigned short*)carve((size_t)NE * ND * NI * 2);
  unsigned short* contrib = (unsigned short*)carve((size_t)NB * NE * NKP * 16 * ND * 2);

  hipMemsetAsync(twt, 0, NB * NT * 4, stream);
  hipMemsetAsync(cnt, 0, NB * NT * 4, stream);

  k_wconv<<<(NE * 768 * ND + 255) / 256, 256, 0, stream>>>(Wgate, Wup, Wdown, wgu, wdb);
  k_fuse<<<12, 128, 0, stream>>>(Wc, Wg, bc, bg, Af, cf);
  k_stats<<<NB * NT, 192, 0, stream>>>(x, ln_g, ln_b, Wg, Af, cf, aff);
  k_topk<<<NB * NE, 256, 0, stream>>>(aff, sidx, sval, twt, cnt, inv);
  k_wtn<<<NB * NE * NKP / 256, 256, 0, stream>>>(sidx, sval, twt, wtn);
  dim3 gffn(NB * NE, 4096 / 64, 1);
  k_ffn<<<gffn, 256, 0, stream>>>(x, wgu, wdb, sidx, wtn, contrib);
  k_scatter<<<NB * NT, 256, 0, stream>>>(contrib, cnt, inv, out);
}